// Round 1
// baseline (180.472 us; speedup 1.0000x reference)
//
#include <hip/hip_runtime.h>
#include <hip/hip_bf16.h>

#define B_    32
#define N_    32
#define S_    52
#define C_    80
#define PLANE (S_*S_)          // 2704
#define TOT   (B_*3*PLANE)     // 259584
#define IGNORE_THR 0.5f

// anchors / stride(=8) for S=52
__device__ __constant__ float d_aw[9] = {14.5f, 19.5f, 46.625f, 3.75f, 7.75f, 7.375f, 1.25f, 2.0f,  4.125f};
__device__ __constant__ float d_ah[9] = {11.25f,24.75f,40.75f,  7.625f,5.625f,14.875f,1.625f,3.75f, 2.875f};

__global__ void kzero(float* res) {
    if (threadIdx.x < 2) res[threadIdx.x] = 0.0f;
}

__global__ void kfix(float* res) {
    res[1] = fmaxf(res[1], 1.0f);
}

__launch_bounds__(256)
__global__ void kmain(const float* __restrict__ pred,
                      const float* __restrict__ tgts,
                      float* __restrict__ res) {
    // LDS-staged per-target data (block spans <=2 batches: 1024 cells < 8112/batch)
    __shared__ float s_ax1[64], s_ay1[64], s_ax2[64], s_ay2[64], s_area[64];
    __shared__ int   s_meta[64];

    const int blkFirst = blockIdx.x * 256 * 4;
    const int blkLast  = min(TOT - 1, blkFirst + 256*4 - 1);
    const int bFirst   = blkFirst / (3*PLANE);
    const int bLastB   = blkLast  / (3*PLANE);
    const int nb       = bLastB - bFirst + 1;   // 1 or 2

    if ((int)threadIdx.x < nb * 32) {
        const int n  = threadIdx.x & 31;
        const int bb = bFirst + (threadIdx.x >> 5);
        const float* tp = tgts + (size_t)(bb*N_ + n)*5;
        const float t0 = tp[0], t1 = tp[1], t2 = tp[2], t3 = tp[3], t4 = tp[4];
        const float gx = t0*0.125f, gy = t1*0.125f, gw = t2*0.125f, gh = t3*0.125f;
        int best = 0; float bestr = -1.0f;
        #pragma unroll
        for (int cc = 0; cc < 9; cc++) {
            const float inter = fminf(gw, d_aw[cc]) * fminf(gh, d_ah[cc]);
            const float uni   = gw*gh + d_aw[cc]*d_ah[cc] - inter;
            const float r     = inter / uni;
            if (r > bestr) { bestr = r; best = cc; }   // first-max tie-break (argmax)
        }
        const int valid = (best >= 6 && best < 9) ? 1 : 0;
        const int gi = (int)floorf(gx);
        const int gj = (int)floorf(gy);
        s_ax1[threadIdx.x]  = gx - gw*0.5f;
        s_ay1[threadIdx.x]  = gy - gh*0.5f;
        s_ax2[threadIdx.x]  = gx + gw*0.5f;
        s_ay2[threadIdx.x]  = gy + gh*0.5f;
        s_area[threadIdx.x] = gw * gh;
        s_meta[threadIdx.x] = valid | (best << 1) | (gi << 5) | (gj << 11) | (((int)t4) << 17);
    }
    __syncthreads();

    float loss = 0.0f, npos = 0.0f;
    const int g0 = (blockIdx.x*256 + threadIdx.x) * 4;
    if (g0 < TOT) {
        const int b   = g0 / (3*PLANE);
        const int r   = g0 - b*3*PLANE;
        const int a   = r / PLANE;
        const int lin = r - a*PLANE;          // multiple of 4; row not crossed (52%4==0)
        const int i   = lin / S_;
        const int j0  = lin - i*S_;

        const float la_w = (a == 0) ? 1.25f  : ((a == 1) ? 2.0f  : 4.125f);
        const float la_h = (a == 0) ? 1.625f : ((a == 1) ? 3.75f : 2.875f);

        const float* base = pred + ((size_t)(b*255 + a*85))*PLANE + lin;
        const float4 P0 = *(const float4*)(base);
        const float4 P1 = *(const float4*)(base + 1*PLANE);
        const float4 P2 = *(const float4*)(base + 2*PLANE);
        const float4 P3 = *(const float4*)(base + 3*PLANE);
        const float4 P4 = *(const float4*)(base + 4*PLANE);
        const float pv0[4] = {P0.x, P0.y, P0.z, P0.w};
        const float pv1[4] = {P1.x, P1.y, P1.z, P1.w};
        const float pv2[4] = {P2.x, P2.y, P2.z, P2.w};
        const float pv3[4] = {P3.x, P3.y, P3.z, P3.w};
        const float pv4[4] = {P4.x, P4.y, P4.z, P4.w};

        float bx1[4], bx2[4], by1[4], by2[4], areab[4];
        #pragma unroll
        for (int c = 0; c < 4; c++) {
            const float px = 1.0f/(1.0f + expf(-pv0[c])) + (float)(j0 + c);
            const float py = 1.0f/(1.0f + expf(-pv1[c])) + (float)i;
            const float pw = expf(pv2[c]) * la_w;
            const float ph = expf(pv3[c]) * la_h;
            bx1[c] = px - pw*0.5f; bx2[c] = px + pw*0.5f;
            by1[c] = py - ph*0.5f; by2[c] = py + ph*0.5f;
            areab[c] = pw * ph;
        }

        float ioumax[4] = {0.f, 0.f, 0.f, 0.f};
        int   lastm[4]  = {-1, -1, -1, -1};
        unsigned long long cm_lo[4] = {0,0,0,0};
        unsigned int       cm_hi[4] = {0,0,0,0};

        const int sbase = (b - bFirst) * 32;
        for (int n = 0; n < N_; n++) {
            const float ax1 = s_ax1[sbase+n], ay1 = s_ay1[sbase+n];
            const float ax2 = s_ax2[sbase+n], ay2 = s_ay2[sbase+n];
            const float ar  = s_area[sbase+n];
            const int meta  = s_meta[sbase+n];
            const int mvalid = meta & 1;
            const int mbest  = (meta >> 1) & 15;
            const int mgi    = (meta >> 5) & 63;
            const int mgj    = (meta >> 11) & 63;
            const int mcls   = (meta >> 17) & 127;
            const bool rowmatch = mvalid && ((mbest - 6) == a) && (mgj == i);
            #pragma unroll
            for (int c = 0; c < 4; c++) {
                float iw = fminf(ax2, bx2[c]) - fmaxf(ax1, bx1[c]);
                float ih = fminf(ay2, by2[c]) - fmaxf(ay1, by1[c]);
                iw = fmaxf(iw, 0.0f); ih = fmaxf(ih, 0.0f);
                const float inter = iw * ih;
                const float iou   = inter / (ar + areab[c] - inter);
                ioumax[c] = fmaxf(ioumax[c], iou);
                if (rowmatch && mgi == (j0 + c)) {
                    lastm[c] = n;   // np last-write-wins
                    if (mcls < 64) cm_lo[c] |= 1ull << mcls;
                    else           cm_hi[c] |= 1u << (mcls - 64);
                }
            }
        }

        const float eps = 1e-7f;
        const float invB = 1.0f / (float)B_;
        #pragma unroll
        for (int c = 0; c < 4; c++) {
            float conf = 1.0f/(1.0f + expf(-pv4[c]));
            conf = fminf(fmaxf(conf, eps), 1.0f - eps);
            if (lastm[c] < 0) {
                // noobj cell (zeroed if ioumax > thr)
                if (ioumax[c] <= IGNORE_THR) loss += -logf(1.0f - conf) * invB;
            } else {
                npos += 1.0f;
                loss += -logf(conf) * invB;               // conf positive term (noobj=0 here)
                // recompute target regression values for the last-matching target
                const float* tp = tgts + (size_t)(b*N_ + lastm[c])*5;
                const float t0 = tp[0], t1 = tp[1], t2 = tp[2], t3 = tp[3];
                const float gx = t0*0.125f, gy = t1*0.125f, gw = t2*0.125f, gh = t3*0.125f;
                const float ttx = gx - floorf(gx);
                const float tty = gy - floorf(gy);
                const int   meta  = s_meta[sbase + lastm[c]];
                const int   mbest = (meta >> 1) & 15;
                const float ttw = logf(gw / d_aw[mbest]);
                const float tth = logf(gh / d_ah[mbest]);
                const float tbls = 2.0f - (t2/416.0f)*(t3/416.0f);   // box_loss_scale

                float x = 1.0f/(1.0f + expf(-pv0[c]));
                float y = 1.0f/(1.0f + expf(-pv1[c]));
                x = fminf(fmaxf(x, eps), 1.0f - eps);
                y = fminf(fmaxf(y, eps), 1.0f - eps);
                const float bx = -ttx*logf(x) - (1.0f - ttx)*logf(1.0f - x);
                const float by = -tty*logf(y) - (1.0f - tty)*logf(1.0f - y);
                const float dw = pv2[c] - ttw;
                const float dh = pv3[c] - tth;
                loss += (bx + by + 0.5f*dw*dw + 0.5f*dh*dh) * tbls * invB;

                // class BCE (only positive cells contribute)
                const float* cbase = pred + ((size_t)(b*255 + a*85 + 5))*PLANE + lin + c;
                #pragma unroll 4
                for (int cc = 0; cc < C_; cc++) {
                    const float z = cbase[(size_t)cc * PLANE];
                    float p = 1.0f/(1.0f + expf(-z));
                    p = fminf(fmaxf(p, eps), 1.0f - eps);
                    const bool t = (cc < 64) ? ((cm_lo[c] >> cc) & 1ull)
                                             : ((cm_hi[c] >> (cc - 64)) & 1u);
                    loss += (t ? -logf(p) : -logf(1.0f - p)) * invB;
                }
            }
        }
    }

    // wave(64)-level reduction, one atomic per wave
    #pragma unroll
    for (int off = 32; off > 0; off >>= 1) {
        loss += __shfl_down(loss, off, 64);
        npos += __shfl_down(npos, off, 64);
    }
    if ((threadIdx.x & 63) == 0) {
        atomicAdd(res + 0, loss);
        atomicAdd(res + 1, npos);
    }
}

extern "C" void kernel_launch(void* const* d_in, const int* in_sizes, int n_in,
                              void* d_out, int out_size, void* d_ws, size_t ws_size,
                              hipStream_t stream) {
    const float* pred = (const float*)d_in[0];   // (32,255,52,52) fp32
    const float* tgts = (const float*)d_in[1];   // (32,32,5) fp32
    float* res = (float*)d_out;                  // [loss, num_pos]

    kzero<<<1, 64, 0, stream>>>(res);
    const int nthreads = TOT / 4;                           // 64896
    const int nblocks  = (nthreads + 255) / 256;            // 254
    kmain<<<nblocks, 256, 0, stream>>>(pred, tgts, res);
    kfix<<<1, 1, 0, stream>>>(res);
}

// Round 2
// 140.439 us; speedup vs baseline: 1.2851x; 1.2851x over previous
//
#include <hip/hip_runtime.h>
#include <hip/hip_bf16.h>

#define B_    32
#define N_    32
#define S_    52
#define C_    80
#define PLANE (S_*S_)          // 2704
#define CPB   (3*PLANE)        // 8112 cells per batch
#define TOT   (B_*CPB)         // 259584 = 1014 * 256 exactly
#define NBLK  (TOT/256)        // 1014
#define IGNORE_THR 0.5f

// anchors / stride(=8) for S=52
__device__ __constant__ float d_aw[9] = {14.5f, 19.5f, 46.625f, 3.75f, 7.75f, 7.375f, 1.25f, 2.0f,  4.125f};
__device__ __constant__ float d_ah[9] = {11.25f,24.75f,40.75f,  7.625f,5.625f,14.875f,1.625f,3.75f, 2.875f};

__global__ void kzero(float* res) {
    if (threadIdx.x < 2) res[threadIdx.x] = 0.0f;
}
__global__ void kfix(float* res) {
    res[1] = fmaxf(res[1], 1.0f);
}

// use_part=1: write per-block partials to part[]; else atomicAdd into res
__launch_bounds__(256)
__global__ void kmain(const float* __restrict__ pred,
                      const float* __restrict__ tgts,
                      float2* __restrict__ part,
                      float* __restrict__ res,
                      int use_part) {
    __shared__ float s_ax1[64], s_ay1[64], s_ax2[64], s_ay2[64], s_area[64];
    __shared__ int   s_meta[64];
    __shared__ float s_red[8];

    const int g   = blockIdx.x*256 + (int)threadIdx.x;   // < TOT exactly
    const int b   = g / CPB;
    const int r   = g - b*CPB;
    const int a   = r / PLANE;
    const int lin = r - a*PLANE;
    const int i   = lin / S_;
    const int j   = lin - i*S_;

    // issue the 5 channel loads early (coalesced: consecutive lanes -> consecutive lin)
    const float* base = pred + ((size_t)(b*255 + a*85))*PLANE + lin;
    const float z0 = base[0];
    const float z1 = base[1*PLANE];
    const float z2 = base[2*PLANE];
    const float z3 = base[3*PLANE];
    const float z4 = base[4*PLANE];

    // stage per-target data for the 1-2 batches this block touches
    const int bFirst = (blockIdx.x*256) / CPB;
    const int bLast  = (blockIdx.x*256 + 255) / CPB;
    const int nb     = bLast - bFirst + 1;
    if ((int)threadIdx.x < nb * 32) {
        const int n  = threadIdx.x & 31;
        const int bb = bFirst + ((int)threadIdx.x >> 5);
        const float* tp = tgts + (size_t)(bb*N_ + n)*5;
        const float t0 = tp[0], t1 = tp[1], t2 = tp[2], t3 = tp[3], t4 = tp[4];
        const float gx = t0*0.125f, gy = t1*0.125f, gw = t2*0.125f, gh = t3*0.125f;
        int best = 0; float bestr = -1.0f;
        #pragma unroll
        for (int cc = 0; cc < 9; cc++) {
            const float inter = fminf(gw, d_aw[cc]) * fminf(gh, d_ah[cc]);
            const float uni   = gw*gh + d_aw[cc]*d_ah[cc] - inter;
            const float rr    = inter / uni;
            if (rr > bestr) { bestr = rr; best = cc; }   // first-max tie-break
        }
        const int valid = (best >= 6 && best < 9) ? 1 : 0;
        const int gi = (int)floorf(gx);
        const int gj = (int)floorf(gy);
        s_ax1[threadIdx.x]  = gx - gw*0.5f;
        s_ay1[threadIdx.x]  = gy - gh*0.5f;
        s_ax2[threadIdx.x]  = gx + gw*0.5f;
        s_ay2[threadIdx.x]  = gy + gh*0.5f;
        s_area[threadIdx.x] = gw * gh;
        s_meta[threadIdx.x] = valid | (best << 1) | (gi << 5) | (gj << 11) | (((int)t4) << 17);
    }
    __syncthreads();

    // predicted box for this cell
    const float la_w = (a == 0) ? 1.25f  : ((a == 1) ? 2.0f  : 4.125f);
    const float la_h = (a == 0) ? 1.625f : ((a == 1) ? 3.75f : 2.875f);
    const float sx = 1.0f/(1.0f + __expf(-z0));
    const float sy = 1.0f/(1.0f + __expf(-z1));
    const float px = sx + (float)j;
    const float py = sy + (float)i;
    const float pw = __expf(z2) * la_w;
    const float ph = __expf(z3) * la_h;
    const float bx1 = px - pw*0.5f, bx2 = px + pw*0.5f;
    const float by1 = py - ph*0.5f, by2 = py + ph*0.5f;
    const float areab = pw * ph;

    // division-free inner loop: iou > 0.5  <=>  3*inter > area_a + area_b
    bool ignore = false;
    int  lastm  = -1;
    unsigned long long cm_lo = 0ull;
    unsigned int       cm_hi = 0u;
    const int sbase = (b - bFirst) * 32;
    #pragma unroll 4
    for (int n = 0; n < N_; n++) {
        const float ax1 = s_ax1[sbase+n], ay1 = s_ay1[sbase+n];
        const float ax2 = s_ax2[sbase+n], ay2 = s_ay2[sbase+n];
        const float ar  = s_area[sbase+n];
        const int meta  = s_meta[sbase+n];
        const float iw = fmaxf(fminf(ax2, bx2) - fmaxf(ax1, bx1), 0.0f);
        const float ih = fmaxf(fminf(ay2, by2) - fmaxf(ay1, by1), 0.0f);
        const float inter = iw * ih;
        ignore = ignore || (3.0f*inter > ar + areab);
        const int mvalid = meta & 1;
        const int mbest  = (meta >> 1) & 15;
        const int mgi    = (meta >> 5) & 63;
        const int mgj    = (meta >> 11) & 63;
        if (mvalid && ((mbest - 6) == a) && (mgj == i) && (mgi == j)) {
            lastm = n;  // np .at[].set last-write-wins
            const int mcls = (meta >> 17) & 127;
            if (mcls < 64) cm_lo |= 1ull << mcls;
            else           cm_hi |= 1u << (mcls - 64);
        }
    }

    const float eps  = 1e-7f;
    const float invB = 1.0f / (float)B_;
    float loss = 0.0f, npos = 0.0f;

    float conf = 1.0f/(1.0f + __expf(-z4));
    conf = fminf(fmaxf(conf, eps), 1.0f - eps);
    if (lastm < 0) {
        if (!ignore) loss = -__logf(1.0f - conf) * invB;
    } else {
        npos = 1.0f;
        loss = -__logf(conf) * invB;
        const float* tp = tgts + (size_t)(b*N_ + lastm)*5;
        const float t0 = tp[0], t1 = tp[1], t2 = tp[2], t3 = tp[3];
        const float gx = t0*0.125f, gy = t1*0.125f, gw = t2*0.125f, gh = t3*0.125f;
        const float ttx = gx - floorf(gx);
        const float tty = gy - floorf(gy);
        const int   meta  = s_meta[sbase + lastm];
        const int   mbest = (meta >> 1) & 15;
        const float ttw = __logf(gw / d_aw[mbest]);
        const float tth = __logf(gh / d_ah[mbest]);
        const float tbls = 2.0f - (t2/416.0f)*(t3/416.0f);

        float x = fminf(fmaxf(sx, eps), 1.0f - eps);
        float y = fminf(fmaxf(sy, eps), 1.0f - eps);
        const float bx = -ttx*__logf(x) - (1.0f - ttx)*__logf(1.0f - x);
        const float by = -tty*__logf(y) - (1.0f - tty)*__logf(1.0f - y);
        const float dw = z2 - ttw;
        const float dh = z3 - tth;
        loss += (bx + by + 0.5f*dw*dw + 0.5f*dh*dh) * tbls * invB;

        const float* cbase = pred + ((size_t)(b*255 + a*85 + 5))*PLANE + lin;
        #pragma unroll 4
        for (int cc = 0; cc < C_; cc++) {
            const float z = cbase[(size_t)cc * PLANE];
            float p = 1.0f/(1.0f + __expf(-z));
            p = fminf(fmaxf(p, eps), 1.0f - eps);
            const bool t = (cc < 64) ? ((cm_lo >> cc) & 1ull)
                                     : ((cm_hi >> (cc - 64)) & 1u);
            loss += (t ? -__logf(p) : -__logf(1.0f - p)) * invB;
        }
    }

    // wave reduce then cross-wave via LDS
    #pragma unroll
    for (int off = 32; off > 0; off >>= 1) {
        loss += __shfl_down(loss, off, 64);
        npos += __shfl_down(npos, off, 64);
    }
    if ((threadIdx.x & 63) == 0) {
        s_red[(threadIdx.x >> 6)*2 + 0] = loss;
        s_red[(threadIdx.x >> 6)*2 + 1] = npos;
    }
    __syncthreads();
    if (threadIdx.x == 0) {
        float L = 0.0f, P = 0.0f;
        #pragma unroll
        for (int w = 0; w < 4; w++) { L += s_red[2*w]; P += s_red[2*w+1]; }
        if (use_part) part[blockIdx.x] = make_float2(L, P);
        else { atomicAdd(res + 0, L); atomicAdd(res + 1, P); }
    }
}

__launch_bounds__(256)
__global__ void kfinal(const float2* __restrict__ part, float* __restrict__ res) {
    __shared__ float s_red[8];
    float L = 0.0f, P = 0.0f;
    for (int k = threadIdx.x; k < NBLK; k += 256) {
        const float2 v = part[k];
        L += v.x; P += v.y;
    }
    #pragma unroll
    for (int off = 32; off > 0; off >>= 1) {
        L += __shfl_down(L, off, 64);
        P += __shfl_down(P, off, 64);
    }
    if ((threadIdx.x & 63) == 0) {
        s_red[(threadIdx.x >> 6)*2 + 0] = L;
        s_red[(threadIdx.x >> 6)*2 + 1] = P;
    }
    __syncthreads();
    if (threadIdx.x == 0) {
        float tl = 0.0f, tp = 0.0f;
        #pragma unroll
        for (int w = 0; w < 4; w++) { tl += s_red[2*w]; tp += s_red[2*w+1]; }
        res[0] = tl;
        res[1] = fmaxf(tp, 1.0f);
    }
}

extern "C" void kernel_launch(void* const* d_in, const int* in_sizes, int n_in,
                              void* d_out, int out_size, void* d_ws, size_t ws_size,
                              hipStream_t stream) {
    const float* pred = (const float*)d_in[0];   // (32,255,52,52) fp32
    const float* tgts = (const float*)d_in[1];   // (32,32,5) fp32
    float* res = (float*)d_out;                  // [loss, num_pos]

    if (ws_size >= (size_t)NBLK * sizeof(float2)) {
        float2* part = (float2*)d_ws;
        kmain<<<NBLK, 256, 0, stream>>>(pred, tgts, part, res, 1);
        kfinal<<<1, 256, 0, stream>>>(part, res);
    } else {
        kzero<<<1, 64, 0, stream>>>(res);
        kmain<<<NBLK, 256, 0, stream>>>(pred, tgts, nullptr, res, 0);
        kfix<<<1, 1, 0, stream>>>(res);
    }
}

// Round 3
// 117.877 us; speedup vs baseline: 1.5310x; 1.1914x over previous
//
#include <hip/hip_runtime.h>
#include <hip/hip_bf16.h>

#define B_    32
#define N_    32
#define S_    52
#define C_    80
#define PLANE (S_*S_)          // 2704
#define CPB   (3*PLANE)        // 8112 cells per batch
#define TOT   (B_*CPB)         // 259584 = 1014 * 256 exactly
#define NBLK  (TOT/256)        // 1014

// anchors / stride(=8) for S=52
__device__ __constant__ float d_aw[9] = {14.5f, 19.5f, 46.625f, 3.75f, 7.75f, 7.375f, 1.25f, 2.0f,  4.125f};
__device__ __constant__ float d_ah[9] = {11.25f,24.75f,40.75f,  7.625f,5.625f,14.875f,1.625f,3.75f, 2.875f};

__global__ void kzero(float* res) {
    if (threadIdx.x < 2) res[threadIdx.x] = 0.0f;
}
__global__ void kfix(float* res) {
    res[1] = fmaxf(res[1], 1.0f);
}

__device__ __forceinline__ float sigm(float z)  { return 1.0f / (1.0f + __expf(-z)); }
__device__ __forceinline__ float clampp(float p){ return fminf(fmaxf(p, 1e-7f), 1.0f - 1e-7f); }

__launch_bounds__(256)
__global__ void kmain(const float* __restrict__ pred,
                      const float* __restrict__ tgts,
                      float2* __restrict__ part,
                      float* __restrict__ res,
                      int use_part) {
    __shared__ float4 s_box[64];   // ax1, ay1, ax2, ay2
    __shared__ float2 s_am[64];    // area, bitcast(meta)  meta = key(14b) | cls<<14
    __shared__ float4 s_reg[64];   // ttx, tty, ttw, tth
    __shared__ float  s_bls[64];   // box_loss_scale
    __shared__ float  s_red[8];

    const int g   = blockIdx.x*256 + (int)threadIdx.x;   // grid covers TOT exactly
    const int b   = g / CPB;
    const int r   = g - b*CPB;
    const int a   = r / PLANE;
    const int lin = r - a*PLANE;
    const int i   = lin / S_;
    const int j   = lin - i*S_;

    // issue the 5 channel loads early (coalesced)
    const int off5 = (b*255 + a*85)*PLANE + lin;
    const float z0 = pred[off5];
    const float z1 = pred[off5 + 1*PLANE];
    const float z2 = pred[off5 + 2*PLANE];
    const float z3 = pred[off5 + 3*PLANE];
    const float z4 = pred[off5 + 4*PLANE];

    // stage per-target data for the 1-2 batches this block touches
    const int bFirst = (blockIdx.x*256) / CPB;
    const int bLast  = (blockIdx.x*256 + 255) / CPB;
    const int nb     = bLast - bFirst + 1;
    if ((int)threadIdx.x < nb * 32) {
        const int n  = threadIdx.x & 31;
        const int bb = bFirst + ((int)threadIdx.x >> 5);
        const float* tp = tgts + (size_t)(bb*N_ + n)*5;
        const float t0 = tp[0], t1 = tp[1], t2 = tp[2], t3 = tp[3], t4 = tp[4];
        const float gx = t0*0.125f, gy = t1*0.125f, gw = t2*0.125f, gh = t3*0.125f;
        int best = 0; float bestr = -1.0f;
        #pragma unroll
        for (int cc = 0; cc < 9; cc++) {
            const float inter = fminf(gw, d_aw[cc]) * fminf(gh, d_ah[cc]);
            const float uni   = gw*gh + d_aw[cc]*d_ah[cc] - inter;
            const float rr    = inter / uni;
            if (rr > bestr) { bestr = rr; best = cc; }   // first-max tie-break
        }
        const int valid = (best >= 6 && best < 9) ? 1 : 0;
        const int gi = (int)floorf(gx);
        const int gj = (int)floorf(gy);
        // match key: a*4096 + i*64 + j  (max 11507 < 16383)
        const int key = valid ? (((best - 6) << 12) | (gj << 6) | gi) : 16383;
        const int meta = key | (((int)t4) << 14);
        s_box[threadIdx.x] = make_float4(gx - gw*0.5f, gy - gh*0.5f, gx + gw*0.5f, gy + gh*0.5f);
        s_am[threadIdx.x]  = make_float2(gw * gh, __int_as_float(meta));
        s_reg[threadIdx.x] = make_float4(gx - (float)gi, gy - (float)gj,
                                         __logf(gw / d_aw[best]), __logf(gh / d_ah[best]));
        s_bls[threadIdx.x] = 2.0f - (t2*(1.0f/416.0f))*(t3*(1.0f/416.0f));
    }
    __syncthreads();

    // predicted box for this cell
    const float la_w = (a == 0) ? 1.25f  : ((a == 1) ? 2.0f  : 4.125f);
    const float la_h = (a == 0) ? 1.625f : ((a == 1) ? 3.75f : 2.875f);
    const float sx = sigm(z0);
    const float sy = sigm(z1);
    const float px = sx + (float)j;
    const float py = sy + (float)i;
    const float pw = __expf(z2) * la_w;
    const float ph = __expf(z3) * la_h;
    const float bx1 = px - pw*0.5f, bx2 = px + pw*0.5f;
    const float by1 = py - ph*0.5f, by2 = py + ph*0.5f;
    const float areab = pw * ph;

    // 32-target loop: division-free ignore test + single-compare match
    bool ignore = false;
    int  lastm  = -1;
    unsigned long long cm_lo = 0ull;
    unsigned int       cm_hi = 0u;
    const int sbase = (b - bFirst) * 32;
    const int mykey = (a << 12) | (i << 6) | j;
    #pragma unroll 8
    for (int n = 0; n < N_; n++) {
        const float4 tb = s_box[sbase+n];
        const float2 am = s_am[sbase+n];
        const int  meta = __float_as_int(am.y);
        const float iw = fmaxf(fminf(tb.z, bx2) - fmaxf(tb.x, bx1), 0.0f);
        const float ih = fmaxf(fminf(tb.w, by2) - fmaxf(tb.y, by1), 0.0f);
        const float inter = iw * ih;
        ignore = ignore || (3.0f*inter > am.x + areab);   // iou > 0.5
        if ((meta & 16383) == mykey) {
            lastm = n;                                     // np last-write-wins
            const int mcls = meta >> 14;
            if (mcls < 64) cm_lo |= 1ull << mcls;
            else           cm_hi |= 1u << (mcls - 64);
        }
    }

    const float invB = 1.0f / (float)B_;
    float loss = 0.0f, npos = 0.0f;

    const float conf = clampp(sigm(z4));
    if (lastm < 0) {
        if (!ignore) loss = -__logf(1.0f - conf) * invB;
    } else {
        npos = 1.0f;
        const float4 rg  = s_reg[sbase + lastm];
        const float  bls = s_bls[sbase + lastm];
        const float x = clampp(sx);
        const float y = clampp(sy);
        const float bx = -rg.x*__logf(x) - (1.0f - rg.x)*__logf(1.0f - x);
        const float by = -rg.y*__logf(y) - (1.0f - rg.y)*__logf(1.0f - y);
        const float dw = z2 - rg.z;
        const float dh = z3 - rg.w;
        loss = (-__logf(conf) + (bx + by + 0.5f*dw*dw + 0.5f*dh*dh) * bls) * invB;
    }

    // wave-cooperative class BCE: iterate positive lanes (uniform loop),
    // 64 lanes split the 80 class-channel loads of each positive cell
    {
        unsigned long long pm = __ballot(lastm >= 0);
        const int lane = (int)(threadIdx.x & 63);
        const int myoff = off5 + 5*PLANE;
        float clsacc = 0.0f;
        while (pm) {
            const int src = __ffsll((unsigned long long)pm) - 1;
            pm &= pm - 1;
            const int soff          = __shfl(myoff, src, 64);
            const unsigned int slo0 = (unsigned int)__shfl((int)(cm_lo & 0xffffffffull), src, 64);
            const unsigned int slo1 = (unsigned int)__shfl((int)(cm_lo >> 32), src, 64);
            const unsigned int shi  = (unsigned int)__shfl((int)cm_hi, src, 64);
            const float za = pred[soff + lane*PLANE];
            const float pa = clampp(sigm(za));
            const bool  ta = (lane < 32) ? ((slo0 >> lane) & 1u) : ((slo1 >> (lane - 32)) & 1u);
            clsacc += ta ? -__logf(pa) : -__logf(1.0f - pa);
            if (lane < 16) {
                const float zb = pred[soff + (64 + lane)*PLANE];
                const float pb = clampp(sigm(zb));
                const bool  tb = (shi >> lane) & 1u;
                clsacc += tb ? -__logf(pb) : -__logf(1.0f - pb);
            }
        }
        loss += clsacc * invB;
    }

    // wave reduce then cross-wave via LDS
    #pragma unroll
    for (int off = 32; off > 0; off >>= 1) {
        loss += __shfl_down(loss, off, 64);
        npos += __shfl_down(npos, off, 64);
    }
    if ((threadIdx.x & 63) == 0) {
        s_red[(threadIdx.x >> 6)*2 + 0] = loss;
        s_red[(threadIdx.x >> 6)*2 + 1] = npos;
    }
    __syncthreads();
    if (threadIdx.x == 0) {
        float L = 0.0f, P = 0.0f;
        #pragma unroll
        for (int w = 0; w < 4; w++) { L += s_red[2*w]; P += s_red[2*w+1]; }
        if (use_part) part[blockIdx.x] = make_float2(L, P);
        else { atomicAdd(res + 0, L); atomicAdd(res + 1, P); }
    }
}

__launch_bounds__(256)
__global__ void kfinal(const float2* __restrict__ part, float* __restrict__ res) {
    __shared__ float s_red[8];
    float L = 0.0f, P = 0.0f;
    for (int k = threadIdx.x; k < NBLK; k += 256) {
        const float2 v = part[k];
        L += v.x; P += v.y;
    }
    #pragma unroll
    for (int off = 32; off > 0; off >>= 1) {
        L += __shfl_down(L, off, 64);
        P += __shfl_down(P, off, 64);
    }
    if ((threadIdx.x & 63) == 0) {
        s_red[(threadIdx.x >> 6)*2 + 0] = L;
        s_red[(threadIdx.x >> 6)*2 + 1] = P;
    }
    __syncthreads();
    if (threadIdx.x == 0) {
        float tl = 0.0f, tp = 0.0f;
        #pragma unroll
        for (int w = 0; w < 4; w++) { tl += s_red[2*w]; tp += s_red[2*w+1]; }
        res[0] = tl;
        res[1] = fmaxf(tp, 1.0f);
    }
}

extern "C" void kernel_launch(void* const* d_in, const int* in_sizes, int n_in,
                              void* d_out, int out_size, void* d_ws, size_t ws_size,
                              hipStream_t stream) {
    const float* pred = (const float*)d_in[0];   // (32,255,52,52) fp32
    const float* tgts = (const float*)d_in[1];   // (32,32,5) fp32
    float* res = (float*)d_out;                  // [loss, num_pos]

    if (ws_size >= (size_t)NBLK * sizeof(float2)) {
        float2* part = (float2*)d_ws;
        kmain<<<NBLK, 256, 0, stream>>>(pred, tgts, part, res, 1);
        kfinal<<<1, 256, 0, stream>>>(part, res);
    } else {
        kzero<<<1, 64, 0, stream>>>(res);
        kmain<<<NBLK, 256, 0, stream>>>(pred, tgts, nullptr, res, 0);
        kfix<<<1, 1, 0, stream>>>(res);
    }
}